// Round 6
// baseline (94.064 us; speedup 1.0000x reference)
//
#include <hip/hip_runtime.h>

#define SDIM 2048
#define DDIM 64
#define BHN  32
#define NQT  32

using f32x4  = __attribute__((ext_vector_type(4))) float;
using f32x16 = __attribute__((ext_vector_type(16))) float;
using bf16x8 = __attribute__((ext_vector_type(8))) __bf16;
using s16x8  = __attribute__((ext_vector_type(8))) short;

union FragU { s16x8 s; bf16x8 b; uint4 u4; };
union US8   { unsigned short u[8]; uint4 v; };
union PW    { __bf16 h[2]; unsigned int u; };

__device__ __forceinline__ unsigned short f2bf(float f) {
    unsigned int u = __builtin_bit_cast(unsigned int, f);
    u += 0x7fffu + ((u >> 16) & 1u);          // round-to-nearest-even
    return (unsigned short)(u >> 16);
}

__device__ __forceinline__ unsigned int packbf(float a, float b) {
    PW w; w.h[0] = (__bf16)a; w.h[1] = (__bf16)b; return w.u;
}

__device__ __forceinline__ void gload16(const void* g, void* l) {
    __builtin_amdgcn_global_load_lds(
        (const __attribute__((address_space(1))) void*)g,
        (__attribute__((address_space(3))) void*)l, 16, 0, 0);
}

// ---------------- pre-pass: K fp32 -> bf16 (row-major) ----------------
__global__ __launch_bounds__(256) void conv_k_kernel(
    const float* __restrict__ K, unsigned short* __restrict__ Kb)
{
    const size_t i = (size_t)blockIdx.x * 256 + threadIdx.x;   // 8 elems each
    const float4* src = (const float4*)(K + i * 8);
    float4 a = src[0], b = src[1];
    US8 o;
    o.u[0] = f2bf(a.x); o.u[1] = f2bf(a.y); o.u[2] = f2bf(a.z); o.u[3] = f2bf(a.w);
    o.u[4] = f2bf(b.x); o.u[5] = f2bf(b.y); o.u[6] = f2bf(b.z); o.u[7] = f2bf(b.w);
    *(uint4*)(Kb + i * 8) = o.v;
}

// ---------------- pre-pass: V fp32 [bh][s][d] -> V^T bf16 [bh][d][s] ----------------
__global__ __launch_bounds__(256) void conv_vt_kernel(
    const float* __restrict__ V, unsigned short* __restrict__ Vt)
{
    const int s0 = blockIdx.x * 64;
    const int bh = blockIdx.y;
    __shared__ unsigned short T[64][66];      // [s][d], padded stride
    const int t = threadIdx.x;
    {
        const int r = t >> 2, seg = t & 3;
        const float* src = V + ((size_t)bh * SDIM + s0 + r) * DDIM + seg * 16;
        float4 f0 = ((const float4*)src)[0];
        float4 f1 = ((const float4*)src)[1];
        float4 f2 = ((const float4*)src)[2];
        float4 f3 = ((const float4*)src)[3];
        float vv[16] = { f0.x, f0.y, f0.z, f0.w, f1.x, f1.y, f1.z, f1.w,
                         f2.x, f2.y, f2.z, f2.w, f3.x, f3.y, f3.z, f3.w };
        #pragma unroll
        for (int j = 0; j < 16; ++j) T[r][seg * 16 + j] = f2bf(vv[j]);
    }
    __syncthreads();
    {
        const int d = t >> 2, q = t & 3;
        US8 w0, w1;
        #pragma unroll
        for (int j = 0; j < 8; ++j) { w0.u[j] = T[q * 16 + j][d]; w1.u[j] = T[q * 16 + 8 + j][d]; }
        unsigned short* dst = Vt + ((size_t)bh * DDIM + d) * SDIM + s0 + q * 16;
        *(uint4*)dst       = w0.v;
        *(uint4*)(dst + 8) = w1.v;
    }
}

// ================= v3: 32x32 swapped QK^T, in-register softmax =================
// S^T = mfma(K, Q): lane holds col q = lane&31, rows k = (r&3)+8*(r>>2)+4*hi (+32 for s1).
// O^T = mfma(V^T, P^T): col q = lane&31 matches softmax state; rescale is lane-uniform.
__device__ __forceinline__ void compute32(
    const unsigned char* __restrict__ Kt, const unsigned char* __restrict__ Vt,
    const FragU* __restrict__ qf, f32x16& o0, f32x16& o1,
    float& m_s, float& l_s, int q_lane, int q0w, int kt64, int l31, int hi)
{
    const int swz = (l31 & 7) << 4;
    const int cb  = hi * 16;

    // ---- QK^T: two 32x32 k-halves, K=64 contraction as 4 chained mfma ----
    f32x16 s0 = {}, s1 = {};
    #pragma unroll
    for (int kc = 0; kc < 4; ++kc) {
        FragU k0f, k1f;
        k0f.u4 = *(const uint4*)&Kt[ l31       * 128 + ((kc * 32 + cb) ^ swz)];
        k1f.u4 = *(const uint4*)&Kt[(l31 + 32) * 128 + ((kc * 32 + cb) ^ swz)];
        s0 = __builtin_amdgcn_mfma_f32_32x32x16_bf16(k0f.b, qf[kc].b, s0, 0, 0, 0);
        s1 = __builtin_amdgcn_mfma_f32_32x32x16_bf16(k1f.b, qf[kc].b, s1, 0, 0, 0);
    }

    // ---- causal mask (wave-uniform gate) ----
    if (kt64 + 63 > q0w) {
        #pragma unroll
        for (int r = 0; r < 16; ++r) {
            const int kl = (r & 3) + 8 * (r >> 2) + 4 * hi;
            if (kt64 + kl      > q_lane) s0[r] = -1e30f;
            if (kt64 + 32 + kl > q_lane) s1[r] = -1e30f;
        }
    }

    // ---- in-register online softmax (log2 domain; q = lane&31) ----
    float m4[4];
    #pragma unroll
    for (int j = 0; j < 4; ++j)
        m4[j] = fmaxf(fmaxf(fmaxf(s0[4*j], s0[4*j+1]), fmaxf(s0[4*j+2], s0[4*j+3])),
                      fmaxf(fmaxf(s1[4*j], s1[4*j+1]), fmaxf(s1[4*j+2], s1[4*j+3])));
    float tmx = fmaxf(fmaxf(m4[0], m4[1]), fmaxf(m4[2], m4[3]));
    tmx = fmaxf(tmx, __shfl_xor(tmx, 32, 64));
    const float mn = fmaxf(m_s, tmx);
    const float cf = exp2f(m_s - mn);
    m_s = mn;
    #pragma unroll
    for (int r = 0; r < 16; ++r) { s0[r] = exp2f(s0[r] - mn); s1[r] = exp2f(s1[r] - mn); }
    float s4[4];
    #pragma unroll
    for (int j = 0; j < 4; ++j)
        s4[j] = ((s0[4*j] + s0[4*j+1]) + (s0[4*j+2] + s0[4*j+3]))
              + ((s1[4*j] + s1[4*j+1]) + (s1[4*j+2] + s1[4*j+3]));
    float rs = (s4[0] + s4[1]) + (s4[2] + s4[3]);
    rs += __shfl_xor(rs, 32, 64);
    l_s = l_s * cf + rs;
    #pragma unroll
    for (int r = 0; r < 16; ++r) { o0[r] *= cf; o1[r] *= cf; }

    // ---- P^T -> bf16 B-fragments via pack + half-exchange ----
    // lane-lo regs {0..3,8..11,...} are k {0..3,8..11,...}; hi-partner holds k+4.
    FragU pa[4];
    const bool lo = (hi == 0);
    #pragma unroll
    for (int h = 0; h < 2; ++h) {
        #pragma unroll
        for (int sub = 0; sub < 2; ++sub) {
            const int e = sub * 8;
            unsigned int a0, a1, b0, b1;
            if (h == 0) {
                a0 = packbf(s0[e+0], s0[e+1]); a1 = packbf(s0[e+2], s0[e+3]);
                b0 = packbf(s0[e+4], s0[e+5]); b1 = packbf(s0[e+6], s0[e+7]);
            } else {
                a0 = packbf(s1[e+0], s1[e+1]); a1 = packbf(s1[e+2], s1[e+3]);
                b0 = packbf(s1[e+4], s1[e+5]); b1 = packbf(s1[e+6], s1[e+7]);
            }
            const unsigned int ta0 = (unsigned int)__shfl_xor((int)a0, 32, 64);
            const unsigned int ta1 = (unsigned int)__shfl_xor((int)a1, 32, 64);
            const unsigned int tb0 = (unsigned int)__shfl_xor((int)b0, 32, 64);
            const unsigned int tb1 = (unsigned int)__shfl_xor((int)b1, 32, 64);
            FragU f;
            f.u4.x = lo ? a0  : tb0;   // k+0,k+1 (lo) / k+8,k+9 (hi)
            f.u4.y = lo ? a1  : tb1;
            f.u4.z = lo ? ta0 : b0;    // k+4,k+5 (lo) / k+12,k+13 (hi)
            f.u4.w = lo ? ta1 : b1;
            pa[h * 2 + sub] = f;
        }
    }

    // ---- O^T += V^T · P^T  (V^T rows = d; output col = q = lane&31) ----
    #pragma unroll
    for (int kc = 0; kc < 4; ++kc) {
        FragU v0f, v1f;
        v0f.u4 = *(const uint4*)&Vt[ l31       * 128 + ((kc * 32 + cb) ^ swz)];
        v1f.u4 = *(const uint4*)&Vt[(l31 + 32) * 128 + ((kc * 32 + cb) ^ swz)];
        o0 = __builtin_amdgcn_mfma_f32_32x32x16_bf16(v0f.b, pa[kc].b, o0, 0, 0, 0);
        o1 = __builtin_amdgcn_mfma_f32_32x32x16_bf16(v1f.b, pa[kc].b, o1, 0, 0, 0);
    }
}

__global__ __launch_bounds__(256, 1) void attn_fwd_v3(
    const float* __restrict__ Q, const unsigned short* __restrict__ Kbf,
    const unsigned short* __restrict__ Vtb, float* __restrict__ O)
{
    const int p    = blockIdx.x;          // 0..7: pair (H=15-p heavy, L=p light)
    const int bh   = blockIdx.y;
    const int H    = 15 - p;
    const int L    = p;
    const int ktmax = 2 * H + 1;
    const int tid  = threadIdx.x;
    const int wid  = tid >> 6;            // wave 0..3 -> 32 q rows each
    const int lane = tid & 63;
    const int l31  = lane & 31;
    const int hi   = lane >> 5;

    __shared__ unsigned char Kl[2][8192];
    __shared__ unsigned char Vl[2][8192];

    const size_t base = (size_t)bh * SDIM * DDIM;
    const int q0B = H * 128 + wid * 32;
    const int q0A = L * 128 + wid * 32;
    const int qBl = q0B + l31, qAl = q0A + l31;

    // Q fragments, scale 1/8 * log2(e) folded (exp2 softmax domain)
    const float qs = 0.125f * 1.44269504088896f;
    FragU qfB[4], qfA[4];
    #pragma unroll
    for (int kc = 0; kc < 4; ++kc) {
        const int d0 = kc * 16 + hi * 8;
        const float* pB = Q + base + (size_t)qBl * DDIM + d0;
        const float* pA = Q + base + (size_t)qAl * DDIM + d0;
        float4 xb = ((const float4*)pB)[0], yb = ((const float4*)pB)[1];
        float4 xa = ((const float4*)pA)[0], ya = ((const float4*)pA)[1];
        qfB[kc].u4 = make_uint4(packbf(xb.x*qs, xb.y*qs), packbf(xb.z*qs, xb.w*qs),
                                packbf(yb.x*qs, yb.y*qs), packbf(yb.z*qs, yb.w*qs));
        qfA[kc].u4 = make_uint4(packbf(xa.x*qs, xa.y*qs), packbf(xa.z*qs, xa.w*qs),
                                packbf(ya.x*qs, ya.y*qs), packbf(ya.z*qs, ya.w*qs));
    }

    f32x16 oB0 = {}, oB1 = {}, oA0 = {}, oA1 = {};
    float mB = -1e30f, lB = 0.f, mA = -1e30f, lA = 0.f;

    const char* Vg = (const char*)(Vtb + (size_t)bh * DDIM * SDIM);
    auto stage = [&](int kt, int sb) {
        const int k0 = kt * 64;
        const char* Kt = (const char*)(Kbf + ((size_t)bh * SDIM + (size_t)k0) * DDIM);
        #pragma unroll
        for (int c = 0; c < 2; ++c) {
            const int db = wid * 2048 + c * 1024 + lane * 16;   // LDS dest byte (linear)
            const int sw = ((db >> 7) & 7) << 4;                // row XOR, bits 4-6
            gload16(Kt + (db ^ sw), &Kl[sb][wid * 2048 + c * 1024]);
            const int d  = db >> 7;
            const int wo = (db & 127) ^ sw;
            gload16(Vg + (size_t)d * (SDIM * 2) + k0 * 2 + wo, &Vl[sb][wid * 2048 + c * 1024]);
        }
    };

    stage(0, 0);
    int bi = 0;
    for (int kt = 0; kt <= ktmax; ++kt) {
        __syncthreads();                       // drains staged loads + prior reads
        if (kt < ktmax) stage(kt + 1, bi ^ 1); // prefetch flies under compute
        const int kt64 = kt * 64;
        if (kt64 <= q0B + 31)
            compute32(Kl[bi], Vl[bi], qfB, oB0, oB1, mB, lB, qBl, q0B, kt64, l31, hi);
        if (kt64 <= q0A + 31)
            compute32(Kl[bi], Vl[bi], qfA, oA0, oA1, mA, lA, qAl, q0A, kt64, l31, hi);
        bi ^= 1;
    }

    // epilogue: O[q][d], d = dt*32 + 8*mq + 4*hi + (0..3)
    const float invB = 1.f / lB, invA = 1.f / lA;
    #pragma unroll
    for (int mq = 0; mq < 4; ++mq) {
        const int dm = mq * 8 + hi * 4;
        float4 w;
        w.x = oB0[4*mq+0]*invB; w.y = oB0[4*mq+1]*invB; w.z = oB0[4*mq+2]*invB; w.w = oB0[4*mq+3]*invB;
        *(float4*)(O + base + (size_t)qBl * DDIM + dm) = w;
        w.x = oB1[4*mq+0]*invB; w.y = oB1[4*mq+1]*invB; w.z = oB1[4*mq+2]*invB; w.w = oB1[4*mq+3]*invB;
        *(float4*)(O + base + (size_t)qBl * DDIM + 32 + dm) = w;
        w.x = oA0[4*mq+0]*invA; w.y = oA0[4*mq+1]*invA; w.z = oA0[4*mq+2]*invA; w.w = oA0[4*mq+3]*invA;
        *(float4*)(O + base + (size_t)qAl * DDIM + dm) = w;
        w.x = oA1[4*mq+0]*invA; w.y = oA1[4*mq+1]*invA; w.z = oA1[4*mq+2]*invA; w.w = oA1[4*mq+3]*invA;
        *(float4*)(O + base + (size_t)qAl * DDIM + 32 + dm) = w;
    }
}

// ---------------- round-1-style fallback (used only if ws too small) ----------------
__global__ __launch_bounds__(256) void attn_fwd_v1(
    const float* __restrict__ Q, const float* __restrict__ K,
    const float* __restrict__ V, float* __restrict__ O)
{
    const int qt   = blockIdx.x;
    const int bh   = blockIdx.y;
    const int tid  = threadIdx.x;
    const int wid  = tid >> 6;
    const int lane = tid & 63;
    const int l15  = lane & 15;
    const int g    = lane >> 4;

    __shared__ unsigned char Klds[64 * 128];
    __shared__ unsigned char Vt[64 * 128];
    __shared__ unsigned char Pl[4][2048];

    const size_t base = (size_t)bh * SDIM * DDIM;
    const int rw0 = qt * 64 + wid * 16;

    FragU qa[2];
    {
        const float* qp = Q + base + (size_t)(rw0 + l15) * DDIM;
        #pragma unroll
        for (int kc = 0; kc < 2; ++kc) {
            const float4* pp = (const float4*)(qp + kc * 32 + g * 8);
            float4 x = pp[0], y = pp[1];
            float f[8] = { x.x, x.y, x.z, x.w, y.x, y.y, y.z, y.w };
            #pragma unroll
            for (int j = 0; j < 8; ++j) qa[kc].s[j] = (short)f2bf(f[j] * 0.125f);
        }
    }

    f32x4 o[4] = {};
    float m_i[4], l_i[4];
    #pragma unroll
    for (int i = 0; i < 4; ++i) { m_i[i] = -1e30f; l_i[i] = 0.f; }

    for (int kt = 0; kt <= qt; ++kt) {
        const int k0 = kt * 64;
        __syncthreads();
        {
            const int row = tid >> 2, seg = tid & 3;
            const float* src = K + base + (size_t)(k0 + row) * DDIM + seg * 16;
            float4 f0 = ((const float4*)src)[0];
            float4 f1 = ((const float4*)src)[1];
            float4 f2 = ((const float4*)src)[2];
            float4 f3 = ((const float4*)src)[3];
            US8 c0, c1;
            c0.u[0]=f2bf(f0.x); c0.u[1]=f2bf(f0.y); c0.u[2]=f2bf(f0.z); c0.u[3]=f2bf(f0.w);
            c0.u[4]=f2bf(f1.x); c0.u[5]=f2bf(f1.y); c0.u[6]=f2bf(f1.z); c0.u[7]=f2bf(f1.w);
            c1.u[0]=f2bf(f2.x); c1.u[1]=f2bf(f2.y); c1.u[2]=f2bf(f2.z); c1.u[3]=f2bf(f2.w);
            c1.u[4]=f2bf(f3.x); c1.u[5]=f2bf(f3.y); c1.u[6]=f2bf(f3.z); c1.u[7]=f2bf(f3.w);
            const int rb = row * 128 + seg * 32;
            const int sw = (row & 7) << 4;
            *(uint4*)&Klds[(rb)      ^ sw] = c0.v;
            *(uint4*)&Klds[(rb + 16) ^ sw] = c1.v;
        }
        {
            const int kv = tid >> 2, seg = tid & 3;
            const float* src = V + base + (size_t)(k0 + kv) * DDIM + seg * 16;
            float4 f0 = ((const float4*)src)[0];
            float4 f1 = ((const float4*)src)[1];
            float4 f2 = ((const float4*)src)[2];
            float4 f3 = ((const float4*)src)[3];
            float vv[16] = { f0.x, f0.y, f0.z, f0.w, f1.x, f1.y, f1.z, f1.w,
                             f2.x, f2.y, f2.z, f2.w, f3.x, f3.y, f3.z, f3.w };
            #pragma unroll
            for (int j = 0; j < 16; ++j) {
                const int dd = seg * 16 + j;
                const int by = dd * 128 + kv * 2;
                *(unsigned short*)&Vt[by ^ ((dd & 7) << 4)] = f2bf(vv[j]);
            }
        }
        __syncthreads();

        f32x4 s[4];
        #pragma unroll
        for (int ct = 0; ct < 4; ++ct) {
            f32x4 acc = {};
            #pragma unroll
            for (int kc = 0; kc < 2; ++kc) {
                const int row = ct * 16 + l15;
                FragU kb;
                kb.u4 = *(const uint4*)&Klds[(row * 128 + (kc * 32 + g * 8) * 2) ^ ((row & 7) << 4)];
                acc = __builtin_amdgcn_mfma_f32_16x16x32_bf16(qa[kc].b, kb.b, acc, 0, 0, 0);
            }
            s[ct] = acc;
        }
        if (kt == qt) {
            #pragma unroll
            for (int ct = 0; ct < 4; ++ct)
                #pragma unroll
                for (int i = 0; i < 4; ++i)
                    if (k0 + ct * 16 + l15 > rw0 + g * 4 + i) s[ct][i] = -1e30f;
        }
        float tm[4];
        #pragma unroll
        for (int i = 0; i < 4; ++i)
            tm[i] = fmaxf(fmaxf(s[0][i], s[1][i]), fmaxf(s[2][i], s[3][i]));
        #pragma unroll
        for (int off = 1; off < 16; off <<= 1)
            #pragma unroll
            for (int i = 0; i < 4; ++i) tm[i] = fmaxf(tm[i], __shfl_xor(tm[i], off, 64));
        float cf[4];
        #pragma unroll
        for (int i = 0; i < 4; ++i) {
            const float mn = fmaxf(m_i[i], tm[i]);
            cf[i] = __expf(m_i[i] - mn);
            m_i[i] = mn;
        }
        #pragma unroll
        for (int ct = 0; ct < 4; ++ct)
            #pragma unroll
            for (int i = 0; i < 4; ++i) s[ct][i] = __expf(s[ct][i] - m_i[i]);
        float rsv[4];
        #pragma unroll
        for (int i = 0; i < 4; ++i) rsv[i] = s[0][i] + s[1][i] + s[2][i] + s[3][i];
        #pragma unroll
        for (int off = 1; off < 16; off <<= 1)
            #pragma unroll
            for (int i = 0; i < 4; ++i) rsv[i] += __shfl_xor(rsv[i], off, 64);
        #pragma unroll
        for (int i = 0; i < 4; ++i) l_i[i] = l_i[i] * cf[i] + rsv[i];
        #pragma unroll
        for (int n = 0; n < 4; ++n)
            #pragma unroll
            for (int i = 0; i < 4; ++i) o[n][i] *= cf[i];

        unsigned char* pw = Pl[wid];
        #pragma unroll
        for (int ct = 0; ct < 4; ++ct)
            #pragma unroll
            for (int i = 0; i < 4; ++i) {
                const int row = g * 4 + i;
                const int by  = row * 128 + (ct * 16 + l15) * 2;
                *(unsigned short*)&pw[by ^ ((row & 7) << 4)] = f2bf(s[ct][i]);
            }
        asm volatile("s_waitcnt lgkmcnt(0)" ::: "memory");
        __builtin_amdgcn_sched_barrier(0);

        #pragma unroll
        for (int kc = 0; kc < 2; ++kc) {
            FragU pafr;
            pafr.u4 = *(const uint4*)&pw[(l15 * 128 + (kc * 32 + g * 8) * 2) ^ ((l15 & 7) << 4)];
            #pragma unroll
            for (int nt = 0; nt < 4; ++nt) {
                const int row = nt * 16 + l15;
                FragU vb;
                vb.u4 = *(const uint4*)&Vt[(row * 128 + (kc * 32 + g * 8) * 2) ^ ((row & 7) << 4)];
                o[nt] = __builtin_amdgcn_mfma_f32_16x16x32_bf16(pafr.b, vb.b, o[nt], 0, 0, 0);
            }
        }
    }

    #pragma unroll
    for (int i = 0; i < 4; ++i) {
        const float inv = 1.0f / l_i[i];
        float* op = O + base + (size_t)(rw0 + g * 4 + i) * DDIM;
        #pragma unroll
        for (int n = 0; n < 4; ++n) op[n * 16 + l15] = o[n][i] * inv;
    }
}

extern "C" void kernel_launch(void* const* d_in, const int* in_sizes, int n_in,
                              void* d_out, int out_size, void* d_ws, size_t ws_size,
                              hipStream_t stream) {
    const float* Q = (const float*)d_in[0];
    const float* K = (const float*)d_in[1];
    const float* V = (const float*)d_in[2];
    float* O = (float*)d_out;

    const size_t tensor_elems = (size_t)BHN * SDIM * DDIM;      // 4.19M
    const size_t need = tensor_elems * 2 * 2;                   // Kbf + Vt, bf16

    if (ws_size >= need) {
        unsigned short* Kb = (unsigned short*)d_ws;
        unsigned short* Vt = Kb + tensor_elems;
        conv_k_kernel<<<dim3((unsigned)(tensor_elems / 8 / 256)), dim3(256), 0, stream>>>(K, Kb);
        conv_vt_kernel<<<dim3(SDIM / 64, BHN), dim3(256), 0, stream>>>(V, Vt);
        attn_fwd_v3<<<dim3(8, BHN), dim3(256), 0, stream>>>(Q, Kb, Vt, O);
    } else {
        attn_fwd_v1<<<dim3(NQT, BHN), dim3(256), 0, stream>>>(Q, K, V, O);
    }
}

// Round 7
// 77.816 us; speedup vs baseline: 1.2088x; 1.2088x over previous
//
#include <hip/hip_runtime.h>

#define SDIM 2048
#define DDIM 64
#define BHN  32
#define NQT  32

using f32x4  = __attribute__((ext_vector_type(4))) float;
using f32x16 = __attribute__((ext_vector_type(16))) float;
using bf16x8 = __attribute__((ext_vector_type(8))) __bf16;
using s16x8  = __attribute__((ext_vector_type(8))) short;

union FragU { s16x8 s; bf16x8 b; uint4 u4; };
union US8   { unsigned short u[8]; uint4 v; };
union PW    { __bf16 h[2]; unsigned int u; };

__device__ __forceinline__ unsigned short f2bf(float f) {
    unsigned int u = __builtin_bit_cast(unsigned int, f);
    u += 0x7fffu + ((u >> 16) & 1u);          // round-to-nearest-even
    return (unsigned short)(u >> 16);
}

__device__ __forceinline__ unsigned int packbf(float a, float b) {
    PW w; w.h[0] = (__bf16)a; w.h[1] = (__bf16)b; return w.u;
}

__device__ __forceinline__ void gload16(const void* g, void* l) {
    __builtin_amdgcn_global_load_lds(
        (const __attribute__((address_space(1))) void*)g,
        (__attribute__((address_space(3))) void*)l, 16, 0, 0);
}

// ---------------- pre-pass: K fp32 -> bf16 (row-major) ----------------
__global__ __launch_bounds__(256) void conv_k_kernel(
    const float* __restrict__ K, unsigned short* __restrict__ Kb)
{
    const size_t i = (size_t)blockIdx.x * 256 + threadIdx.x;   // 8 elems each
    const float4* src = (const float4*)(K + i * 8);
    float4 a = src[0], b = src[1];
    US8 o;
    o.u[0] = f2bf(a.x); o.u[1] = f2bf(a.y); o.u[2] = f2bf(a.z); o.u[3] = f2bf(a.w);
    o.u[4] = f2bf(b.x); o.u[5] = f2bf(b.y); o.u[6] = f2bf(b.z); o.u[7] = f2bf(b.w);
    *(uint4*)(Kb + i * 8) = o.v;
}

// ---------------- pre-pass: V fp32 [bh][s][d] -> V^T bf16 [bh][d][s] ----------------
__global__ __launch_bounds__(256) void conv_vt_kernel(
    const float* __restrict__ V, unsigned short* __restrict__ Vt)
{
    const int s0 = blockIdx.x * 64;
    const int bh = blockIdx.y;
    __shared__ unsigned short T[64][66];      // [s][d], padded stride
    const int t = threadIdx.x;
    {
        const int r = t >> 2, seg = t & 3;
        const float* src = V + ((size_t)bh * SDIM + s0 + r) * DDIM + seg * 16;
        float4 f0 = ((const float4*)src)[0];
        float4 f1 = ((const float4*)src)[1];
        float4 f2 = ((const float4*)src)[2];
        float4 f3 = ((const float4*)src)[3];
        float vv[16] = { f0.x, f0.y, f0.z, f0.w, f1.x, f1.y, f1.z, f1.w,
                         f2.x, f2.y, f2.z, f2.w, f3.x, f3.y, f3.z, f3.w };
        #pragma unroll
        for (int j = 0; j < 16; ++j) T[r][seg * 16 + j] = f2bf(vv[j]);
    }
    __syncthreads();
    {
        const int d = t >> 2, q = t & 3;
        US8 w0, w1;
        #pragma unroll
        for (int j = 0; j < 8; ++j) { w0.u[j] = T[q * 16 + j][d]; w1.u[j] = T[q * 16 + 8 + j][d]; }
        unsigned short* dst = Vt + ((size_t)bh * DDIM + d) * SDIM + s0 + q * 16;
        *(uint4*)dst       = w0.v;
        *(uint4*)(dst + 8) = w1.v;
    }
}

// ================= 32x32 swapped QK^T, in-register softmax =================
// S^T = mfma(K, Q): lane holds col q = lane&31, rows k = (r&3)+8*(r>>2)+4*hi (+32 for s1).
// O^T = mfma(V^T, P^T): col q = lane&31 matches softmax state; rescale is lane-uniform.
__device__ __forceinline__ void compute32(
    const unsigned char* __restrict__ Kt, const unsigned char* __restrict__ Vt,
    const FragU* __restrict__ qf, f32x16& o0, f32x16& o1,
    float& m_s, float& l_s, int q_lane, int q0w, int kt64, int l31, int hi)
{
    const int swz = (l31 & 7) << 4;
    const int cb  = hi * 16;

    // ---- QK^T: two 32x32 k-halves, K=64 contraction as 4 chained mfma ----
    f32x16 s0 = {}, s1 = {};
    #pragma unroll
    for (int kc = 0; kc < 4; ++kc) {
        FragU k0f, k1f;
        k0f.u4 = *(const uint4*)&Kt[ l31       * 128 + ((kc * 32 + cb) ^ swz)];
        k1f.u4 = *(const uint4*)&Kt[(l31 + 32) * 128 + ((kc * 32 + cb) ^ swz)];
        s0 = __builtin_amdgcn_mfma_f32_32x32x16_bf16(k0f.b, qf[kc].b, s0, 0, 0, 0);
        s1 = __builtin_amdgcn_mfma_f32_32x32x16_bf16(k1f.b, qf[kc].b, s1, 0, 0, 0);
    }

    // ---- causal mask (wave-uniform gate) ----
    if (kt64 + 63 > q0w) {
        #pragma unroll
        for (int r = 0; r < 16; ++r) {
            const int kl = (r & 3) + 8 * (r >> 2) + 4 * hi;
            if (kt64 + kl      > q_lane) s0[r] = -1e30f;
            if (kt64 + 32 + kl > q_lane) s1[r] = -1e30f;
        }
    }

    // ---- in-register online softmax (log2 domain; q = lane&31) ----
    float m4[4];
    #pragma unroll
    for (int j = 0; j < 4; ++j)
        m4[j] = fmaxf(fmaxf(fmaxf(s0[4*j], s0[4*j+1]), fmaxf(s0[4*j+2], s0[4*j+3])),
                      fmaxf(fmaxf(s1[4*j], s1[4*j+1]), fmaxf(s1[4*j+2], s1[4*j+3])));
    float tmx = fmaxf(fmaxf(m4[0], m4[1]), fmaxf(m4[2], m4[3]));
    tmx = fmaxf(tmx, __shfl_xor(tmx, 32, 64));
    const float mn = fmaxf(m_s, tmx);
    const float cf = exp2f(m_s - mn);
    m_s = mn;
    #pragma unroll
    for (int r = 0; r < 16; ++r) { s0[r] = exp2f(s0[r] - mn); s1[r] = exp2f(s1[r] - mn); }
    float s4[4];
    #pragma unroll
    for (int j = 0; j < 4; ++j)
        s4[j] = ((s0[4*j] + s0[4*j+1]) + (s0[4*j+2] + s0[4*j+3]))
              + ((s1[4*j] + s1[4*j+1]) + (s1[4*j+2] + s1[4*j+3]));
    float rs = (s4[0] + s4[1]) + (s4[2] + s4[3]);
    rs += __shfl_xor(rs, 32, 64);
    l_s = l_s * cf + rs;
    #pragma unroll
    for (int r = 0; r < 16; ++r) { o0[r] *= cf; o1[r] *= cf; }

    // ---- P^T -> bf16 B-fragments via pack + half-exchange ----
    // lane-lo regs {0..3,8..11,...} are k {0..3,8..11,...}; hi-partner holds k+4.
    FragU pa[4];
    const bool lo = (hi == 0);
    #pragma unroll
    for (int h = 0; h < 2; ++h) {
        #pragma unroll
        for (int sub = 0; sub < 2; ++sub) {
            const int e = sub * 8;
            unsigned int a0, a1, b0, b1;
            if (h == 0) {
                a0 = packbf(s0[e+0], s0[e+1]); a1 = packbf(s0[e+2], s0[e+3]);
                b0 = packbf(s0[e+4], s0[e+5]); b1 = packbf(s0[e+6], s0[e+7]);
            } else {
                a0 = packbf(s1[e+0], s1[e+1]); a1 = packbf(s1[e+2], s1[e+3]);
                b0 = packbf(s1[e+4], s1[e+5]); b1 = packbf(s1[e+6], s1[e+7]);
            }
            const unsigned int ta0 = (unsigned int)__shfl_xor((int)a0, 32, 64);
            const unsigned int ta1 = (unsigned int)__shfl_xor((int)a1, 32, 64);
            const unsigned int tb0 = (unsigned int)__shfl_xor((int)b0, 32, 64);
            const unsigned int tb1 = (unsigned int)__shfl_xor((int)b1, 32, 64);
            FragU f;
            f.u4.x = lo ? a0  : tb0;   // k+0,k+1 (lo) / k+8,k+9 (hi)
            f.u4.y = lo ? a1  : tb1;
            f.u4.z = lo ? ta0 : b0;    // k+4,k+5 (lo) / k+12,k+13 (hi)
            f.u4.w = lo ? ta1 : b1;
            pa[h * 2 + sub] = f;
        }
    }

    // ---- O^T += V^T · P^T  (V^T rows = d; output col = q = lane&31) ----
    #pragma unroll
    for (int kc = 0; kc < 4; ++kc) {
        FragU v0f, v1f;
        v0f.u4 = *(const uint4*)&Vt[ l31       * 128 + ((kc * 32 + cb) ^ swz)];
        v1f.u4 = *(const uint4*)&Vt[(l31 + 32) * 128 + ((kc * 32 + cb) ^ swz)];
        o0 = __builtin_amdgcn_mfma_f32_32x32x16_bf16(v0f.b, pa[kc].b, o0, 0, 0, 0);
        o1 = __builtin_amdgcn_mfma_f32_32x32x16_bf16(v1f.b, pa[kc].b, o1, 0, 0, 0);
    }
}

// ======= v4: 2-wave blocks, one 64-row q-tile each, 2048 waves total =======
__global__ __launch_bounds__(128, 3) void attn_fwd_v4(
    const float* __restrict__ Q, const unsigned short* __restrict__ Kbf,
    const unsigned short* __restrict__ Vtb, float* __restrict__ O)
{
    const int bh = blockIdx.y;
    // balance: CUs receive blocks at linear-id steps of 256 (y steps of 8);
    // alternating identity/reverse by (bh&8) gives each CU {x,31-x,x,31-x}
    // -> per-CU causal work is a constant 66 kv-tile units.
    const int qt = (bh & 8) ? (31 - (int)blockIdx.x) : (int)blockIdx.x;
    const int tid  = threadIdx.x;
    const int wid  = tid >> 6;            // wave 0..1 -> 32 q rows each
    const int lane = tid & 63;
    const int l31  = lane & 31;
    const int hi   = lane >> 5;

    __shared__ unsigned char Kl[2][8192];
    __shared__ unsigned char Vl[2][8192];

    const size_t base = (size_t)bh * SDIM * DDIM;
    const int q0  = qt * 64 + wid * 32;   // this wave's strip base
    const int ql  = q0 + l31;             // this lane's q row
    const int ktmax = qt;

    // Q fragments, scale 1/8 * log2(e) folded (exp2 softmax domain)
    const float qs = 0.125f * 1.44269504088896f;
    FragU qf[4];
    #pragma unroll
    for (int kc = 0; kc < 4; ++kc) {
        const int d0 = kc * 16 + hi * 8;
        const float* pQ = Q + base + (size_t)ql * DDIM + d0;
        float4 x = ((const float4*)pQ)[0], y = ((const float4*)pQ)[1];
        qf[kc].u4 = make_uint4(packbf(x.x*qs, x.y*qs), packbf(x.z*qs, x.w*qs),
                               packbf(y.x*qs, y.y*qs), packbf(y.z*qs, y.w*qs));
    }

    f32x16 o0 = {}, o1 = {};
    float m_s = -1e30f, l_s = 0.f;

    const char* Vg = (const char*)(Vtb + (size_t)bh * DDIM * SDIM);
    auto stage = [&](int kt, int sb) {
        const int k0 = kt * 64;
        const char* Kt = (const char*)(Kbf + ((size_t)bh * SDIM + (size_t)k0) * DDIM);
        #pragma unroll
        for (int c = 0; c < 4; ++c) {
            const int lb = c * 2048 + wid * 1024;               // wave-uniform LDS base
            const int db = lb + lane * 16;                      // this lane's dest byte
            const int sw = ((db >> 7) & 7) << 4;                // row XOR, bits 4-6
            gload16(Kt + (db ^ sw), &Kl[sb][lb]);
            const int d  = db >> 7;
            const int wo = (db & 127) ^ sw;
            gload16(Vg + (size_t)d * (SDIM * 2) + k0 * 2 + wo, &Vl[sb][lb]);
        }
    };

    stage(0, 0);
    int bi = 0;
    for (int kt = 0; kt <= ktmax; ++kt) {
        __syncthreads();                       // drains staged loads + prior reads
        if (kt < ktmax) stage(kt + 1, bi ^ 1); // prefetch flies under compute
        compute32(Kl[bi], Vl[bi], qf, o0, o1, m_s, l_s, ql, q0, kt * 64, l31, hi);
        bi ^= 1;
    }

    // epilogue: O[q][d], d = 32*half + 8*mq + 4*hi + (0..3)
    const float inv = 1.f / l_s;
    #pragma unroll
    for (int mq = 0; mq < 4; ++mq) {
        const int dm = mq * 8 + hi * 4;
        float4 w;
        w.x = o0[4*mq+0]*inv; w.y = o0[4*mq+1]*inv; w.z = o0[4*mq+2]*inv; w.w = o0[4*mq+3]*inv;
        *(float4*)(O + base + (size_t)ql * DDIM + dm) = w;
        w.x = o1[4*mq+0]*inv; w.y = o1[4*mq+1]*inv; w.z = o1[4*mq+2]*inv; w.w = o1[4*mq+3]*inv;
        *(float4*)(O + base + (size_t)ql * DDIM + 32 + dm) = w;
    }
}

// ---------------- round-1-style fallback (used only if ws too small) ----------------
__global__ __launch_bounds__(256) void attn_fwd_v1(
    const float* __restrict__ Q, const float* __restrict__ K,
    const float* __restrict__ V, float* __restrict__ O)
{
    const int qt   = blockIdx.x;
    const int bh   = blockIdx.y;
    const int tid  = threadIdx.x;
    const int wid  = tid >> 6;
    const int lane = tid & 63;
    const int l15  = lane & 15;
    const int g    = lane >> 4;

    __shared__ unsigned char Klds[64 * 128];
    __shared__ unsigned char Vt[64 * 128];
    __shared__ unsigned char Pl[4][2048];

    const size_t base = (size_t)bh * SDIM * DDIM;
    const int rw0 = qt * 64 + wid * 16;

    FragU qa[2];
    {
        const float* qp = Q + base + (size_t)(rw0 + l15) * DDIM;
        #pragma unroll
        for (int kc = 0; kc < 2; ++kc) {
            const float4* pp = (const float4*)(qp + kc * 32 + g * 8);
            float4 x = pp[0], y = pp[1];
            float f[8] = { x.x, x.y, x.z, x.w, y.x, y.y, y.z, y.w };
            #pragma unroll
            for (int j = 0; j < 8; ++j) qa[kc].s[j] = (short)f2bf(f[j] * 0.125f);
        }
    }

    f32x4 o[4] = {};
    float m_i[4], l_i[4];
    #pragma unroll
    for (int i = 0; i < 4; ++i) { m_i[i] = -1e30f; l_i[i] = 0.f; }

    for (int kt = 0; kt <= qt; ++kt) {
        const int k0 = kt * 64;
        __syncthreads();
        {
            const int row = tid >> 2, seg = tid & 3;
            const float* src = K + base + (size_t)(k0 + row) * DDIM + seg * 16;
            float4 f0 = ((const float4*)src)[0];
            float4 f1 = ((const float4*)src)[1];
            float4 f2 = ((const float4*)src)[2];
            float4 f3 = ((const float4*)src)[3];
            US8 c0, c1;
            c0.u[0]=f2bf(f0.x); c0.u[1]=f2bf(f0.y); c0.u[2]=f2bf(f0.z); c0.u[3]=f2bf(f0.w);
            c0.u[4]=f2bf(f1.x); c0.u[5]=f2bf(f1.y); c0.u[6]=f2bf(f1.z); c0.u[7]=f2bf(f1.w);
            c1.u[0]=f2bf(f2.x); c1.u[1]=f2bf(f2.y); c1.u[2]=f2bf(f2.z); c1.u[3]=f2bf(f2.w);
            c1.u[4]=f2bf(f3.x); c1.u[5]=f2bf(f3.y); c1.u[6]=f2bf(f3.z); c1.u[7]=f2bf(f3.w);
            const int rb = row * 128 + seg * 32;
            const int sw = (row & 7) << 4;
            *(uint4*)&Klds[(rb)      ^ sw] = c0.v;
            *(uint4*)&Klds[(rb + 16) ^ sw] = c1.v;
        }
        {
            const int kv = tid >> 2, seg = tid & 3;
            const float* src = V + base + (size_t)(k0 + kv) * DDIM + seg * 16;
            float4 f0 = ((const float4*)src)[0];
            float4 f1 = ((const float4*)src)[1];
            float4 f2 = ((const float4*)src)[2];
            float4 f3 = ((const float4*)src)[3];
            float vv[16] = { f0.x, f0.y, f0.z, f0.w, f1.x, f1.y, f1.z, f1.w,
                             f2.x, f2.y, f2.z, f2.w, f3.x, f3.y, f3.z, f3.w };
            #pragma unroll
            for (int j = 0; j < 16; ++j) {
                const int dd = seg * 16 + j;
                const int by = dd * 128 + kv * 2;
                *(unsigned short*)&Vt[by ^ ((dd & 7) << 4)] = f2bf(vv[j]);
            }
        }
        __syncthreads();

        f32x4 s[4];
        #pragma unroll
        for (int ct = 0; ct < 4; ++ct) {
            f32x4 acc = {};
            #pragma unroll
            for (int kc = 0; kc < 2; ++kc) {
                const int row = ct * 16 + l15;
                FragU kb;
                kb.u4 = *(const uint4*)&Klds[(row * 128 + (kc * 32 + g * 8) * 2) ^ ((row & 7) << 4)];
                acc = __builtin_amdgcn_mfma_f32_16x16x32_bf16(qa[kc].b, kb.b, acc, 0, 0, 0);
            }
            s[ct] = acc;
        }
        if (kt == qt) {
            #pragma unroll
            for (int ct = 0; ct < 4; ++ct)
                #pragma unroll
                for (int i = 0; i < 4; ++i)
                    if (k0 + ct * 16 + l15 > rw0 + g * 4 + i) s[ct][i] = -1e30f;
        }
        float tm[4];
        #pragma unroll
        for (int i = 0; i < 4; ++i)
            tm[i] = fmaxf(fmaxf(s[0][i], s[1][i]), fmaxf(s[2][i], s[3][i]));
        #pragma unroll
        for (int off = 1; off < 16; off <<= 1)
            #pragma unroll
            for (int i = 0; i < 4; ++i) tm[i] = fmaxf(tm[i], __shfl_xor(tm[i], off, 64));
        float cf[4];
        #pragma unroll
        for (int i = 0; i < 4; ++i) {
            const float mn = fmaxf(m_i[i], tm[i]);
            cf[i] = __expf(m_i[i] - mn);
            m_i[i] = mn;
        }
        #pragma unroll
        for (int ct = 0; ct < 4; ++ct)
            #pragma unroll
            for (int i = 0; i < 4; ++i) s[ct][i] = __expf(s[ct][i] - m_i[i]);
        float rsv[4];
        #pragma unroll
        for (int i = 0; i < 4; ++i) rsv[i] = s[0][i] + s[1][i] + s[2][i] + s[3][i];
        #pragma unroll
        for (int off = 1; off < 16; off <<= 1)
            #pragma unroll
            for (int i = 0; i < 4; ++i) rsv[i] += __shfl_xor(rsv[i], off, 64);
        #pragma unroll
        for (int i = 0; i < 4; ++i) l_i[i] = l_i[i] * cf[i] + rsv[i];
        #pragma unroll
        for (int n = 0; n < 4; ++n)
            #pragma unroll
            for (int i = 0; i < 4; ++i) o[n][i] *= cf[i];

        unsigned char* pw = Pl[wid];
        #pragma unroll
        for (int ct = 0; ct < 4; ++ct)
            #pragma unroll
            for (int i = 0; i < 4; ++i) {
                const int row = g * 4 + i;
                const int by  = row * 128 + (ct * 16 + l15) * 2;
                *(unsigned short*)&pw[by ^ ((row & 7) << 4)] = f2bf(s[ct][i]);
            }
        asm volatile("s_waitcnt lgkmcnt(0)" ::: "memory");
        __builtin_amdgcn_sched_barrier(0);

        #pragma unroll
        for (int kc = 0; kc < 2; ++kc) {
            FragU pafr;
            pafr.u4 = *(const uint4*)&pw[(l15 * 128 + (kc * 32 + g * 8) * 2) ^ ((l15 & 7) << 4)];
            #pragma unroll
            for (int nt = 0; nt < 4; ++nt) {
                const int row = nt * 16 + l15;
                FragU vb;
                vb.u4 = *(const uint4*)&Vt[(row * 128 + (kc * 32 + g * 8) * 2) ^ ((row & 7) << 4)];
                o[nt] = __builtin_amdgcn_mfma_f32_16x16x32_bf16(pafr.b, vb.b, o[nt], 0, 0, 0);
            }
        }
    }

    #pragma unroll
    for (int i = 0; i < 4; ++i) {
        const float inv = 1.0f / l_i[i];
        float* op = O + base + (size_t)(rw0 + g * 4 + i) * DDIM;
        #pragma unroll
        for (int n = 0; n < 4; ++n) op[n * 16 + l15] = o[n][i] * inv;
    }
}

extern "C" void kernel_launch(void* const* d_in, const int* in_sizes, int n_in,
                              void* d_out, int out_size, void* d_ws, size_t ws_size,
                              hipStream_t stream) {
    const float* Q = (const float*)d_in[0];
    const float* K = (const float*)d_in[1];
    const float* V = (const float*)d_in[2];
    float* O = (float*)d_out;

    const size_t tensor_elems = (size_t)BHN * SDIM * DDIM;      // 4.19M
    const size_t need = tensor_elems * 2 * 2;                   // Kbf + Vt, bf16

    if (ws_size >= need) {
        unsigned short* Kb = (unsigned short*)d_ws;
        unsigned short* Vt = Kb + tensor_elems;
        conv_k_kernel<<<dim3((unsigned)(tensor_elems / 8 / 256)), dim3(256), 0, stream>>>(K, Kb);
        conv_vt_kernel<<<dim3(SDIM / 64, BHN), dim3(256), 0, stream>>>(V, Vt);
        attn_fwd_v4<<<dim3(NQT, BHN), dim3(128), 0, stream>>>(Q, Kb, Vt, O);
    } else {
        attn_fwd_v1<<<dim3(NQT, BHN), dim3(256), 0, stream>>>(Q, K, V, O);
    }
}

// Round 9
// 76.149 us; speedup vs baseline: 1.2353x; 1.0219x over previous
//
#include <hip/hip_runtime.h>

#define SDIM 2048
#define DDIM 64
#define BHN  32
#define NQT  32

using f32x4  = __attribute__((ext_vector_type(4))) float;
using f32x16 = __attribute__((ext_vector_type(16))) float;
using bf16x8 = __attribute__((ext_vector_type(8))) __bf16;
using s16x8  = __attribute__((ext_vector_type(8))) short;

union FragU { s16x8 s; bf16x8 b; uint4 u4; };
union US8   { unsigned short u[8]; uint4 v; };
union PW    { __bf16 h[2]; unsigned int u; };

__device__ __forceinline__ unsigned short f2bf(float f) {
    unsigned int u = __builtin_bit_cast(unsigned int, f);
    u += 0x7fffu + ((u >> 16) & 1u);          // round-to-nearest-even
    return (unsigned short)(u >> 16);
}

__device__ __forceinline__ unsigned int packbf(float a, float b) {
    PW w; w.h[0] = (__bf16)a; w.h[1] = (__bf16)b; return w.u;
}

__device__ __forceinline__ void gload16(const void* g, void* l) {
    __builtin_amdgcn_global_load_lds(
        (const __attribute__((address_space(1))) void*)g,
        (__attribute__((address_space(3))) void*)l, 16, 0, 0);
}

// ---------------- pre-pass: K fp32 -> bf16 (row-major) ----------------
__global__ __launch_bounds__(256) void conv_k_kernel(
    const float* __restrict__ K, unsigned short* __restrict__ Kb)
{
    const size_t i = (size_t)blockIdx.x * 256 + threadIdx.x;   // 8 elems each
    const float4* src = (const float4*)(K + i * 8);
    float4 a = src[0], b = src[1];
    US8 o;
    o.u[0] = f2bf(a.x); o.u[1] = f2bf(a.y); o.u[2] = f2bf(a.z); o.u[3] = f2bf(a.w);
    o.u[4] = f2bf(b.x); o.u[5] = f2bf(b.y); o.u[6] = f2bf(b.z); o.u[7] = f2bf(b.w);
    *(uint4*)(Kb + i * 8) = o.v;
}

// ---------------- pre-pass: V fp32 [bh][s][d] -> V^T bf16 [bh][d][s] ----------------
__global__ __launch_bounds__(256) void conv_vt_kernel(
    const float* __restrict__ V, unsigned short* __restrict__ Vt)
{
    const int s0 = blockIdx.x * 64;
    const int bh = blockIdx.y;
    __shared__ unsigned short T[64][66];      // [s][d], padded stride
    const int t = threadIdx.x;
    {
        const int r = t >> 2, seg = t & 3;
        const float* src = V + ((size_t)bh * SDIM + s0 + r) * DDIM + seg * 16;
        float4 f0 = ((const float4*)src)[0];
        float4 f1 = ((const float4*)src)[1];
        float4 f2 = ((const float4*)src)[2];
        float4 f3 = ((const float4*)src)[3];
        float vv[16] = { f0.x, f0.y, f0.z, f0.w, f1.x, f1.y, f1.z, f1.w,
                         f2.x, f2.y, f2.z, f2.w, f3.x, f3.y, f3.z, f3.w };
        #pragma unroll
        for (int j = 0; j < 16; ++j) T[r][seg * 16 + j] = f2bf(vv[j]);
    }
    __syncthreads();
    {
        const int d = t >> 2, q = t & 3;
        US8 w0, w1;
        #pragma unroll
        for (int j = 0; j < 8; ++j) { w0.u[j] = T[q * 16 + j][d]; w1.u[j] = T[q * 16 + 8 + j][d]; }
        unsigned short* dst = Vt + ((size_t)bh * DDIM + d) * SDIM + s0 + q * 16;
        *(uint4*)dst       = w0.v;
        *(uint4*)(dst + 8) = w1.v;
    }
}

// ================= 32x32 swapped QK^T, in-register softmax =================
// S^T = mfma(K, Q): lane holds col q = lane&31, rows k = (r&3)+8*(r>>2)+4*hi (+32 for s1).
// O^T = mfma(V^T, P^T): col q = lane&31 matches softmax state; rescale lane-uniform.
__device__ __forceinline__ void compute32(
    const unsigned char* __restrict__ Kt, const unsigned char* __restrict__ Vt,
    const FragU* __restrict__ qf, f32x16& o0, f32x16& o1, f32x16& lacc,
    float& m_s, int q_lane, int q0w, int kt64, int l31, int hi)
{
    const int swz = (l31 & 7) << 4;
    const int cb  = hi * 16;

    // ---- QK^T: two 32x32 k-halves, K=64 contraction as 4 chained mfma ----
    f32x16 s0 = {}, s1 = {};
    __builtin_amdgcn_s_setprio(1);
    #pragma unroll
    for (int kc = 0; kc < 4; ++kc) {
        FragU k0f, k1f;
        k0f.u4 = *(const uint4*)&Kt[ l31       * 128 + ((kc * 32 + cb) ^ swz)];
        k1f.u4 = *(const uint4*)&Kt[(l31 + 32) * 128 + ((kc * 32 + cb) ^ swz)];
        s0 = __builtin_amdgcn_mfma_f32_32x32x16_bf16(k0f.b, qf[kc].b, s0, 0, 0, 0);
        s1 = __builtin_amdgcn_mfma_f32_32x32x16_bf16(k1f.b, qf[kc].b, s1, 0, 0, 0);
    }
    __builtin_amdgcn_s_setprio(0);

    // ---- V fragments early: independent of softmax, hide LDS latency ----
    FragU vf0[4], vf1[4];
    #pragma unroll
    for (int kc = 0; kc < 4; ++kc) {
        vf0[kc].u4 = *(const uint4*)&Vt[ l31       * 128 + ((kc * 32 + cb) ^ swz)];
        vf1[kc].u4 = *(const uint4*)&Vt[(l31 + 32) * 128 + ((kc * 32 + cb) ^ swz)];
    }

    // ---- causal mask (wave-uniform gate) ----
    if (kt64 + 63 > q0w) {
        #pragma unroll
        for (int r = 0; r < 16; ++r) {
            const int kl = (r & 3) + 8 * (r >> 2) + 4 * hi;
            if (kt64 + kl      > q_lane) s0[r] = -1e30f;
            if (kt64 + 32 + kl > q_lane) s1[r] = -1e30f;
        }
    }

    // ---- tile max (in-register tree + verified cross-half shfl) ----
    float m4[4];
    #pragma unroll
    for (int j = 0; j < 4; ++j)
        m4[j] = fmaxf(fmaxf(fmaxf(s0[4*j], s0[4*j+1]), fmaxf(s0[4*j+2], s0[4*j+3])),
                      fmaxf(fmaxf(s1[4*j], s1[4*j+1]), fmaxf(s1[4*j+2], s1[4*j+3])));
    float tmx = fmaxf(fmaxf(m4[0], m4[1]), fmaxf(m4[2], m4[3]));
    tmx = fmaxf(tmx, __shfl_xor(tmx, 32, 64));

    // ---- defer-max (T13, THR=8): skip rescale when growth small ----
    float mn = m_s;
    if (!__all(tmx <= m_s + 8.0f)) {
        mn = fmaxf(m_s, tmx);
        const float cf = exp2f(m_s - mn);
        m_s = mn;
        #pragma unroll
        for (int r = 0; r < 16; ++r) { o0[r] *= cf; o1[r] *= cf; lacc[r] *= cf; }
    }
    #pragma unroll
    for (int r = 0; r < 16; ++r) { s0[r] = exp2f(s0[r] - mn); s1[r] = exp2f(s1[r] - mn); }
    // deferred row-sum: element-wise accumulate, reduce once at the end
    #pragma unroll
    for (int r = 0; r < 16; ++r) lacc[r] += s0[r] + s1[r];

    // ---- P^T -> bf16 B-fragments via pack + half-exchange (v4-verified) ----
    // lane-lo regs {0..3,8..11,...} are k {0..3,8..11,...}; hi-partner holds k+4.
    FragU pa[4];
    const bool lo = (hi == 0);
    #pragma unroll
    for (int h = 0; h < 2; ++h) {
        #pragma unroll
        for (int sub = 0; sub < 2; ++sub) {
            const int e = sub * 8;
            unsigned int a0, a1, b0, b1;
            if (h == 0) {
                a0 = packbf(s0[e+0], s0[e+1]); a1 = packbf(s0[e+2], s0[e+3]);
                b0 = packbf(s0[e+4], s0[e+5]); b1 = packbf(s0[e+6], s0[e+7]);
            } else {
                a0 = packbf(s1[e+0], s1[e+1]); a1 = packbf(s1[e+2], s1[e+3]);
                b0 = packbf(s1[e+4], s1[e+5]); b1 = packbf(s1[e+6], s1[e+7]);
            }
            const unsigned int ta0 = (unsigned int)__shfl_xor((int)a0, 32, 64);
            const unsigned int ta1 = (unsigned int)__shfl_xor((int)a1, 32, 64);
            const unsigned int tb0 = (unsigned int)__shfl_xor((int)b0, 32, 64);
            const unsigned int tb1 = (unsigned int)__shfl_xor((int)b1, 32, 64);
            FragU f;
            f.u4.x = lo ? a0  : tb0;   // k+0,k+1 (lo) / k+8,k+9 (hi)
            f.u4.y = lo ? a1  : tb1;
            f.u4.z = lo ? ta0 : b0;    // k+4,k+5 (lo) / k+12,k+13 (hi)
            f.u4.w = lo ? ta1 : b1;
            pa[h * 2 + sub] = f;
        }
    }

    // ---- O^T += V^T · P^T ----
    __builtin_amdgcn_s_setprio(1);
    #pragma unroll
    for (int kc = 0; kc < 4; ++kc) {
        o0 = __builtin_amdgcn_mfma_f32_32x32x16_bf16(vf0[kc].b, pa[kc].b, o0, 0, 0, 0);
        o1 = __builtin_amdgcn_mfma_f32_32x32x16_bf16(vf1[kc].b, pa[kc].b, o1, 0, 0, 0);
    }
    __builtin_amdgcn_s_setprio(0);
}

// ======= v6: v4 grid + deferred-l + defer-max + early V (shfl verified) =======
__global__ __launch_bounds__(128, 2) void attn_fwd_v6(
    const float* __restrict__ Q, const unsigned short* __restrict__ Kbf,
    const unsigned short* __restrict__ Vtb, float* __restrict__ O)
{
    const int bh = blockIdx.y;
    // per-CU balance: CUs receive blocks at y-steps of 8; alternating
    // identity/reverse by (bh&8) gives each CU {x,31-x,x,31-x}.
    const int qt = (bh & 8) ? (31 - (int)blockIdx.x) : (int)blockIdx.x;
    const int tid  = threadIdx.x;
    const int wid  = tid >> 6;            // wave 0..1 -> 32 q rows each
    const int lane = tid & 63;
    const int l31  = lane & 31;
    const int hi   = lane >> 5;

    __shared__ unsigned char Kl[2][8192];
    __shared__ unsigned char Vl[2][8192];

    const size_t base = (size_t)bh * SDIM * DDIM;
    const int q0  = qt * 64 + wid * 32;   // this wave's strip base
    const int ql  = q0 + l31;             // this lane's q row
    const int ktmax = qt;

    // Q fragments, scale 1/8 * log2(e) folded (exp2 softmax domain)
    const float qs = 0.125f * 1.44269504088896f;
    FragU qf[4];
    #pragma unroll
    for (int kc = 0; kc < 4; ++kc) {
        const int d0 = kc * 16 + hi * 8;
        const float* pQ = Q + base + (size_t)ql * DDIM + d0;
        float4 x = ((const float4*)pQ)[0], y = ((const float4*)pQ)[1];
        qf[kc].u4 = make_uint4(packbf(x.x*qs, x.y*qs), packbf(x.z*qs, x.w*qs),
                               packbf(y.x*qs, y.y*qs), packbf(y.z*qs, y.w*qs));
    }

    f32x16 o0 = {}, o1 = {}, lacc = {};
    float m_s = -1e30f;

    const char* Vg = (const char*)(Vtb + (size_t)bh * DDIM * SDIM);
    auto stage = [&](int kt, int sb) {
        const int k0 = kt * 64;
        const char* Kt = (const char*)(Kbf + ((size_t)bh * SDIM + (size_t)k0) * DDIM);
        #pragma unroll
        for (int c = 0; c < 4; ++c) {
            const int lb = c * 2048 + wid * 1024;               // wave-uniform LDS base
            const int db = lb + lane * 16;                      // this lane's dest byte
            const int sw = ((db >> 7) & 7) << 4;                // row XOR, bits 4-6
            gload16(Kt + (db ^ sw), &Kl[sb][lb]);
            const int d  = db >> 7;
            const int wo = (db & 127) ^ sw;
            gload16(Vg + (size_t)d * (SDIM * 2) + k0 * 2 + wo, &Vl[sb][lb]);
        }
    };

    stage(0, 0);
    int bi = 0;
    for (int kt = 0; kt <= ktmax; ++kt) {
        __syncthreads();                       // drains staged loads + prior reads
        if (kt < ktmax) stage(kt + 1, bi ^ 1); // prefetch flies under compute
        compute32(Kl[bi], Vl[bi], qf, o0, o1, lacc, m_s, ql, q0, kt * 64, l31, hi);
        bi ^= 1;
    }

    // ---- epilogue: reduce deferred l, normalize, store ----
    float l_s = ((lacc[0]+lacc[1])+(lacc[2]+lacc[3])) + ((lacc[4]+lacc[5])+(lacc[6]+lacc[7]))
              + ((lacc[8]+lacc[9])+(lacc[10]+lacc[11])) + ((lacc[12]+lacc[13])+(lacc[14]+lacc[15]));
    l_s += __shfl_xor(l_s, 32, 64);
    const float inv = 1.f / l_s;
    #pragma unroll
    for (int mq = 0; mq < 4; ++mq) {
        const int dm = mq * 8 + hi * 4;
        float4 w;
        w.x = o0[4*mq+0]*inv; w.y = o0[4*mq+1]*inv; w.z = o0[4*mq+2]*inv; w.w = o0[4*mq+3]*inv;
        *(float4*)(O + base + (size_t)ql * DDIM + dm) = w;
        w.x = o1[4*mq+0]*inv; w.y = o1[4*mq+1]*inv; w.z = o1[4*mq+2]*inv; w.w = o1[4*mq+3]*inv;
        *(float4*)(O + base + (size_t)ql * DDIM + 32 + dm) = w;
    }
}

// ---------------- round-1-style fallback (used only if ws too small) ----------------
__global__ __launch_bounds__(256) void attn_fwd_v1(
    const float* __restrict__ Q, const float* __restrict__ K,
    const float* __restrict__ V, float* __restrict__ O)
{
    const int qt   = blockIdx.x;
    const int bh   = blockIdx.y;
    const int tid  = threadIdx.x;
    const int wid  = tid >> 6;
    const int lane = tid & 63;
    const int l15  = lane & 15;
    const int g    = lane >> 4;

    __shared__ unsigned char Klds[64 * 128];
    __shared__ unsigned char Vt[64 * 128];
    __shared__ unsigned char Pl[4][2048];

    const size_t base = (size_t)bh * SDIM * DDIM;
    const int rw0 = qt * 64 + wid * 16;

    FragU qa[2];
    {
        const float* qp = Q + base + (size_t)(rw0 + l15) * DDIM;
        #pragma unroll
        for (int kc = 0; kc < 2; ++kc) {
            const float4* pp = (const float4*)(qp + kc * 32 + g * 8);
            float4 x = pp[0], y = pp[1];
            float f[8] = { x.x, x.y, x.z, x.w, y.x, y.y, y.z, y.w };
            #pragma unroll
            for (int j = 0; j < 8; ++j) qa[kc].s[j] = (short)f2bf(f[j] * 0.125f);
        }
    }

    f32x4 o[4] = {};
    float m_i[4], l_i[4];
    #pragma unroll
    for (int i = 0; i < 4; ++i) { m_i[i] = -1e30f; l_i[i] = 0.f; }

    for (int kt = 0; kt <= qt; ++kt) {
        const int k0 = kt * 64;
        __syncthreads();
        {
            const int row = tid >> 2, seg = tid & 3;
            const float* src = K + base + (size_t)(k0 + row) * DDIM + seg * 16;
            float4 f0 = ((const float4*)src)[0];
            float4 f1 = ((const float4*)src)[1];
            float4 f2 = ((const float4*)src)[2];
            float4 f3 = ((const float4*)src)[3];
            US8 c0, c1;
            c0.u[0]=f2bf(f0.x); c0.u[1]=f2bf(f0.y); c0.u[2]=f2bf(f0.z); c0.u[3]=f2bf(f0.w);
            c0.u[4]=f2bf(f1.x); c0.u[5]=f2bf(f1.y); c0.u[6]=f2bf(f1.z); c0.u[7]=f2bf(f1.w);
            c1.u[0]=f2bf(f2.x); c1.u[1]=f2bf(f2.y); c1.u[2]=f2bf(f2.z); c1.u[3]=f2bf(f2.w);
            c1.u[4]=f2bf(f3.x); c1.u[5]=f2bf(f3.y); c1.u[6]=f2bf(f3.z); c1.u[7]=f2bf(f3.w);
            const int rb = row * 128 + seg * 32;
            const int sw = (row & 7) << 4;
            *(uint4*)&Klds[(rb)      ^ sw] = c0.v;
            *(uint4*)&Klds[(rb + 16) ^ sw] = c1.v;
        }
        {
            const int kv = tid >> 2, seg = tid & 3;
            const float* src = V + base + (size_t)(k0 + kv) * DDIM + seg * 16;
            float4 f0 = ((const float4*)src)[0];
            float4 f1 = ((const float4*)src)[1];
            float4 f2 = ((const float4*)src)[2];
            float4 f3 = ((const float4*)src)[3];
            float vv[16] = { f0.x, f0.y, f0.z, f0.w, f1.x, f1.y, f1.z, f1.w,
                             f2.x, f2.y, f2.z, f2.w, f3.x, f3.y, f3.z, f3.w };
            #pragma unroll
            for (int j = 0; j < 16; ++j) {
                const int dd = seg * 16 + j;
                const int by = dd * 128 + kv * 2;
                *(unsigned short*)&Vt[by ^ ((dd & 7) << 4)] = f2bf(vv[j]);
            }
        }
        __syncthreads();

        f32x4 s[4];
        #pragma unroll
        for (int ct = 0; ct < 4; ++ct) {
            f32x4 acc = {};
            #pragma unroll
            for (int kc = 0; kc < 2; ++kc) {
                const int row = ct * 16 + l15;
                FragU kb;
                kb.u4 = *(const uint4*)&Klds[(row * 128 + (kc * 32 + g * 8) * 2) ^ ((row & 7) << 4)];
                acc = __builtin_amdgcn_mfma_f32_16x16x32_bf16(qa[kc].b, kb.b, acc, 0, 0, 0);
            }
            s[ct] = acc;
        }
        if (kt == qt) {
            #pragma unroll
            for (int ct = 0; ct < 4; ++ct)
                #pragma unroll
                for (int i = 0; i < 4; ++i)
                    if (k0 + ct * 16 + l15 > rw0 + g * 4 + i) s[ct][i] = -1e30f;
        }
        float tm[4];
        #pragma unroll
        for (int i = 0; i < 4; ++i)
            tm[i] = fmaxf(fmaxf(s[0][i], s[1][i]), fmaxf(s[2][i], s[3][i]));
        #pragma unroll
        for (int off = 1; off < 16; off <<= 1)
            #pragma unroll
            for (int i = 0; i < 4; ++i) tm[i] = fmaxf(tm[i], __shfl_xor(tm[i], off, 64));
        float cf[4];
        #pragma unroll
        for (int i = 0; i < 4; ++i) {
            const float mn = fmaxf(m_i[i], tm[i]);
            cf[i] = __expf(m_i[i] - mn);
            m_i[i] = mn;
        }
        #pragma unroll
        for (int ct = 0; ct < 4; ++ct)
            #pragma unroll
            for (int i = 0; i < 4; ++i) s[ct][i] = __expf(s[ct][i] - m_i[i]);
        float rsv[4];
        #pragma unroll
        for (int i = 0; i < 4; ++i) rsv[i] = s[0][i] + s[1][i] + s[2][i] + s[3][i];
        #pragma unroll
        for (int off = 1; off < 16; off <<= 1)
            #pragma unroll
            for (int i = 0; i < 4; ++i) rsv[i] += __shfl_xor(rsv[i], off, 64);
        #pragma unroll
        for (int i = 0; i < 4; ++i) l_i[i] = l_i[i] * cf[i] + rsv[i];
        #pragma unroll
        for (int n = 0; n < 4; ++n)
            #pragma unroll
            for (int i = 0; i < 4; ++i) o[n][i] *= cf[i];

        unsigned char* pw = Pl[wid];
        #pragma unroll
        for (int ct = 0; ct < 4; ++ct)
            #pragma unroll
            for (int i = 0; i < 4; ++i) {
                const int row = g * 4 + i;
                const int by  = row * 128 + (ct * 16 + l15) * 2;
                *(unsigned short*)&pw[by ^ ((row & 7) << 4)] = f2bf(s[ct][i]);
            }
        asm volatile("s_waitcnt lgkmcnt(0)" ::: "memory");
        __builtin_amdgcn_sched_barrier(0);

        #pragma unroll
        for (int kc = 0; kc < 2; ++kc) {
            FragU pafr;
            pafr.u4 = *(const uint4*)&pw[(l15 * 128 + (kc * 32 + g * 8) * 2) ^ ((l15 & 7) << 4)];
            #pragma unroll
            for (int nt = 0; nt < 4; ++nt) {
                const int row = nt * 16 + l15;
                FragU vb;
                vb.u4 = *(const uint4*)&Vt[(row * 128 + (kc * 32 + g * 8) * 2) ^ ((row & 7) << 4)];
                o[nt] = __builtin_amdgcn_mfma_f32_16x16x32_bf16(pafr.b, vb.b, o[nt], 0, 0, 0);
            }
        }
    }

    #pragma unroll
    for (int i = 0; i < 4; ++i) {
        const float inv = 1.0f / l_i[i];
        float* op = O + base + (size_t)(rw0 + g * 4 + i) * DDIM;
        #pragma unroll
        for (int n = 0; n < 4; ++n) op[n * 16 + l15] = o[n][i] * inv;
    }
}

extern "C" void kernel_launch(void* const* d_in, const int* in_sizes, int n_in,
                              void* d_out, int out_size, void* d_ws, size_t ws_size,
                              hipStream_t stream) {
    const float* Q = (const float*)d_in[0];
    const float* K = (const float*)d_in[1];
    const float* V = (const float*)d_in[2];
    float* O = (float*)d_out;

    const size_t tensor_elems = (size_t)BHN * SDIM * DDIM;      // 4.19M
    const size_t need = tensor_elems * 2 * 2;                   // Kbf + Vt, bf16

    if (ws_size >= need) {
        unsigned short* Kb = (unsigned short*)d_ws;
        unsigned short* Vt = Kb + tensor_elems;
        conv_k_kernel<<<dim3((unsigned)(tensor_elems / 8 / 256)), dim3(256), 0, stream>>>(K, Kb);
        conv_vt_kernel<<<dim3(SDIM / 64, BHN), dim3(256), 0, stream>>>(V, Vt);
        attn_fwd_v6<<<dim3(NQT, BHN), dim3(128), 0, stream>>>(Q, Kb, Vt, O);
    } else {
        attn_fwd_v1<<<dim3(NQT, BHN), dim3(256), 0, stream>>>(Q, K, V, O);
    }
}